// Round 1
// baseline (113.550 us; speedup 1.0000x reference)
//
#include <hip/hip_runtime.h>
#include <hip/hip_fp16.h>

// Problem constants (match reference)
constexpr int kHW = 1024 * 1024;
constexpr int kB  = 4;
constexpr int kQuadsPerImage = kHW / 4;            // 262144 = 2^18
constexpr int kM  = 17;
constexpr int kM3 = kM * kM * kM;                  // 4913 cells

constexpr int kBlock   = 512;
constexpr int kGrid    = 1024;
constexpr int kThreads = kBlock * kGrid;           // 524288 threads -> exactly 2 quads each

typedef float f32x4 __attribute__((ext_vector_type(4)));

__device__ __forceinline__ float h2f_lo(unsigned int u) {
    __half2 h = *reinterpret_cast<__half2*>(&u);
    return __low2float(h);
}

// 1D LUT lerp from pre-paired LDS table: s1[c*64+i] = (l[i], l[i+1])  (fp32, exact)
__device__ __forceinline__ float apply1d(const float2* __restrict__ s1, int c, float v) {
    float xs = v * 63.0f;
    int i0 = (int)xs;
    i0 = min(max(i0, 0), 62);
    float f = xs - (float)i0;
    float2 p = s1[(c << 6) + i0];
    return fmaf(f, p.y - p.x, p.x);
}

struct F3 { float x, y, z; };

// Trilinear from fp16-packed LDS LUT: s3[cell] = {h(c0)|h(c1), h(c2)|0}
__device__ __forceinline__ F3 tri3d(const uint2* __restrict__ s3,
                                    float yr, float yg, float yb) {
    float xr = yr * 16.0f, xg = yg * 16.0f, xb = yb * 16.0f;
    int ir = min((int)xr, 15);
    int ig = min((int)xg, 15);
    int ib = min((int)xb, 15);
    float fr = xr - (float)ir;
    float fg = xg - (float)ig;
    float fb = xb - (float)ib;

    const int cell = (ir * 17 + ig) * 17 + ib;      // db=1, dg=17, dr=289

    // One ds_read2_b64 per (r,g) corner pair fetches both b corners.
    auto blerp = [&](const uint2* __restrict__ p) -> F3 {
        uint2 e0 = p[0];   // b corner
        uint2 e1 = p[1];   // b+1 corner
        float2 a01 = __half22float2(*reinterpret_cast<__half2*>(&e0.x));
        float  a2  = h2f_lo(e0.y);
        float2 b01 = __half22float2(*reinterpret_cast<__half2*>(&e1.x));
        float  b2  = h2f_lo(e1.y);
        F3 r;
        r.x = fmaf(fb, b01.x - a01.x, a01.x);
        r.y = fmaf(fb, b01.y - a01.y, a01.y);
        r.z = fmaf(fb, b2 - a2, a2);
        return r;
    };

    F3 v00 = blerp(s3 + cell);            // (r0,g0)
    F3 v01 = blerp(s3 + cell + 17);       // (r0,g1)
    F3 v10 = blerp(s3 + cell + 289);      // (r1,g0)
    F3 v11 = blerp(s3 + cell + 306);      // (r1,g1)

    F3 v0, v1, vf;
    v0.x = fmaf(fg, v01.x - v00.x, v00.x);
    v0.y = fmaf(fg, v01.y - v00.y, v00.y);
    v0.z = fmaf(fg, v01.z - v00.z, v00.z);
    v1.x = fmaf(fg, v11.x - v10.x, v10.x);
    v1.y = fmaf(fg, v11.y - v10.y, v10.y);
    v1.z = fmaf(fg, v11.z - v10.z, v10.z);
    vf.x = fmaf(fr, v1.x - v0.x, v0.x);
    vf.y = fmaf(fr, v1.y - v0.y, v0.y);
    vf.z = fmaf(fr, v1.z - v0.z, v0.z);
    return vf;
}

__device__ __forceinline__ void process_quad(const float2* __restrict__ s1,
                                             const uint2*  __restrict__ s3,
                                             f32x4 r4, f32x4 g4, f32x4 b4,
                                             f32x4& ro, f32x4& go, f32x4& bo)
{
    #pragma unroll
    for (int k = 0; k < 4; ++k) {
        float yr = apply1d(s1, 0, r4[k]);
        float yg = apply1d(s1, 1, g4[k]);
        float yb = apply1d(s1, 2, b4[k]);
        yr = fminf(fmaxf(yr, 0.0f), 1.0f);
        yg = fminf(fmaxf(yg, 0.0f), 1.0f);
        yb = fminf(fmaxf(yb, 0.0f), 1.0f);

        F3 v = tri3d(s3, yr, yg, yb);
        ro[k] = v.x; go[k] = v.y; bo[k] = v.z;
    }
}

// No forced min-waves bound: LDS (40.8 KB) caps residency anyway; a silent
// VGPR spill to scratch would hurt a BW-bound kernel more than lost occupancy.
__global__ __launch_bounds__(kBlock) void lut_apply_kernel(
    const float* __restrict__ x,
    const float* __restrict__ lut1d,   // [3][64]
    const float* __restrict__ lut3d,   // [17][17][17][3]
    float* __restrict__ out)
{
    __shared__ uint2  s3[kM3];         // 39,304 B  fp16-packed 3D LUT
    __shared__ float2 s1[3 * 64];      //  1,536 B  fp32 paired 1D LUT

    for (int i = threadIdx.x; i < kM3; i += kBlock) {
        float c0 = lut3d[3 * i], c1 = lut3d[3 * i + 1], c2 = lut3d[3 * i + 2];
        __half2 h01 = __floats2half2_rn(c0, c1);
        __half2 h2p = __floats2half2_rn(c2, 0.0f);
        uint2 e;
        e.x = *reinterpret_cast<unsigned int*>(&h01);
        e.y = *reinterpret_cast<unsigned int*>(&h2p);
        s3[i] = e;
    }
    for (int i = threadIdx.x; i < 3 * 64; i += kBlock) {
        int c = i >> 6, j = i & 63;
        float a = lut1d[(c << 6) + j];
        float b = lut1d[(c << 6) + (j < 63 ? j + 1 : 63)];
        s1[i] = make_float2(a, b);
    }
    __syncthreads();

    const int t = blockIdx.x * kBlock + threadIdx.x;

    // Exact cover: thread t owns quads t and t + kThreads (no loop, no tail).
    const int q0 = t;
    const int q1 = t + kThreads;

    const int b0 = q0 >> 18, r0 = q0 & (kQuadsPerImage - 1);
    const int b1 = q1 >> 18, r1 = q1 & (kQuadsPerImage - 1);

    const size_t pR0 = (size_t)(b0 * 3 + 0) * kHW + 4 * (size_t)r0;
    const size_t pG0 = (size_t)(b0 * 3 + 1) * kHW + 4 * (size_t)r0;
    const size_t pB0 = (size_t)(b0 * 3 + 2) * kHW + 4 * (size_t)r0;
    const size_t pR1 = (size_t)(b1 * 3 + 0) * kHW + 4 * (size_t)r1;
    const size_t pG1 = (size_t)(b1 * 3 + 1) * kHW + 4 * (size_t)r1;
    const size_t pB1 = (size_t)(b1 * 3 + 2) * kHW + 4 * (size_t)r1;

    // Issue all six 16B streaming loads up front: 96 B in flight per thread,
    // 8 independent pixel chains of ILP to hide HBM + LDS-gather latency.
    const f32x4 ar = __builtin_nontemporal_load((const f32x4*)(x + pR0));
    const f32x4 ag = __builtin_nontemporal_load((const f32x4*)(x + pG0));
    const f32x4 ab = __builtin_nontemporal_load((const f32x4*)(x + pB0));
    const f32x4 cr = __builtin_nontemporal_load((const f32x4*)(x + pR1));
    const f32x4 cg = __builtin_nontemporal_load((const f32x4*)(x + pG1));
    const f32x4 cb = __builtin_nontemporal_load((const f32x4*)(x + pB1));

    f32x4 oR0, oG0, oB0;
    process_quad(s1, s3, ar, ag, ab, oR0, oG0, oB0);
    __builtin_nontemporal_store(oR0, (f32x4*)(out + pR0));
    __builtin_nontemporal_store(oG0, (f32x4*)(out + pG0));
    __builtin_nontemporal_store(oB0, (f32x4*)(out + pB0));

    f32x4 oR1, oG1, oB1;
    process_quad(s1, s3, cr, cg, cb, oR1, oG1, oB1);
    __builtin_nontemporal_store(oR1, (f32x4*)(out + pR1));
    __builtin_nontemporal_store(oG1, (f32x4*)(out + pG1));
    __builtin_nontemporal_store(oB1, (f32x4*)(out + pB1));
}

extern "C" void kernel_launch(void* const* d_in, const int* in_sizes, int n_in,
                              void* d_out, int out_size, void* d_ws, size_t ws_size,
                              hipStream_t stream) {
    const float* x     = (const float*)d_in[0];
    const float* lut1d = (const float*)d_in[1];
    const float* lut3d = (const float*)d_in[2];
    float* out = (float*)d_out;

    hipLaunchKernelGGL(lut_apply_kernel, dim3(kGrid), dim3(kBlock), 0, stream,
                       x, lut1d, lut3d, out);
}

// Round 3
// 111.202 us; speedup vs baseline: 1.0211x; 1.0211x over previous
//
#include <hip/hip_runtime.h>
#include <hip/hip_fp16.h>

// Problem constants (match reference)
constexpr int kHW = 1024 * 1024;
constexpr int kB  = 4;
constexpr int kPairsPerImage = kHW / 2;             // 524288 = 2^19
constexpr int kNPair = kB * kPairsPerImage;         // 2097152 float2-chunks
constexpr int kM  = 17;
constexpr int kM3 = kM * kM * kM;                   // 4913 cells

constexpr int kBlock = 512;
constexpr int kGrid  = 1024;                        // exactly 4 blocks/CU resident on 256 CUs

// clang's nontemporal builtins require scalar/ext_vector types (NOT the
// HIP_vector_type float2 struct) -- round-2 compile failure.
typedef float f32x2 __attribute__((ext_vector_type(2)));

__device__ __forceinline__ float h2f_lo(unsigned int u) {
    __half2 h = *reinterpret_cast<__half2*>(&u);
    return __low2float(h);
}

// 1D LUT lerp from pre-paired LDS table: s1[c*64+i] = (l[i], l[i+1])  (fp32, exact)
__device__ __forceinline__ float apply1d(const float2* __restrict__ s1, int c, float v) {
    float xs = v * 63.0f;
    int i0 = (int)xs;
    i0 = min(max(i0, 0), 62);
    float f = xs - (float)i0;
    float2 p = s1[(c << 6) + i0];
    return fmaf(f, p.y - p.x, p.x);
}

struct F3 { float x, y, z; };

// Trilinear from fp16-packed LDS LUT: s3[cell] = {h(c0)|h(c1), h(c2)|0}
__device__ __forceinline__ F3 tri3d(const uint2* __restrict__ s3,
                                    float yr, float yg, float yb) {
    float xr = yr * 16.0f, xg = yg * 16.0f, xb = yb * 16.0f;
    int ir = min((int)xr, 15);
    int ig = min((int)xg, 15);
    int ib = min((int)xb, 15);
    float fr = xr - (float)ir;
    float fg = xg - (float)ig;
    float fb = xb - (float)ib;

    const int cell = (ir * 17 + ig) * 17 + ib;      // db=1, dg=17, dr=289

    // One ds_read2_b64 per (r,g) corner pair fetches both b corners.
    auto blerp = [&](const uint2* __restrict__ p) -> F3 {
        uint2 e0 = p[0];   // b corner
        uint2 e1 = p[1];   // b+1 corner
        float2 a01 = __half22float2(*reinterpret_cast<__half2*>(&e0.x));
        float  a2  = h2f_lo(e0.y);
        float2 b01 = __half22float2(*reinterpret_cast<__half2*>(&e1.x));
        float  b2  = h2f_lo(e1.y);
        F3 r;
        r.x = fmaf(fb, b01.x - a01.x, a01.x);
        r.y = fmaf(fb, b01.y - a01.y, a01.y);
        r.z = fmaf(fb, b2 - a2, a2);
        return r;
    };

    F3 v00 = blerp(s3 + cell);            // (r0,g0)
    F3 v01 = blerp(s3 + cell + 17);       // (r0,g1)
    F3 v10 = blerp(s3 + cell + 289);      // (r1,g0)
    F3 v11 = blerp(s3 + cell + 306);      // (r1,g1)

    F3 v0, v1, vf;
    v0.x = fmaf(fg, v01.x - v00.x, v00.x);
    v0.y = fmaf(fg, v01.y - v00.y, v00.y);
    v0.z = fmaf(fg, v01.z - v00.z, v00.z);
    v1.x = fmaf(fg, v11.x - v10.x, v10.x);
    v1.y = fmaf(fg, v11.y - v10.y, v10.y);
    v1.z = fmaf(fg, v11.z - v10.z, v10.z);
    vf.x = fmaf(fr, v1.x - v0.x, v0.x);
    vf.y = fmaf(fr, v1.y - v0.y, v0.y);
    vf.z = fmaf(fr, v1.z - v0.z, v0.z);
    return vf;
}

// __launch_bounds__(512, 8): min 8 waves/EU -> 64-VGPR cap. Essential:
// LDS is 40,840 B (rounds to 40,960 = 160KiB/4), so 4 blocks/CU fit IFF
// VGPRs <= 64. Round-1 A/B: removing this bound cost ~30% (occupancy
// 8 -> ~4 waves/SIMD; the random-LDS-gather latency stops being hidden).
__global__ __launch_bounds__(kBlock, 8) void lut_apply_kernel(
    const float* __restrict__ x,
    const float* __restrict__ lut1d,   // [3][64]
    const float* __restrict__ lut3d,   // [17][17][17][3]
    float* __restrict__ out)
{
    __shared__ uint2  s3[kM3];         // 39,304 B  fp16-packed 3D LUT
    __shared__ float2 s1[3 * 64];      //  1,536 B  fp32 paired 1D LUT
                                       // total 40,840 B -> 4 blocks/CU

    for (int i = threadIdx.x; i < kM3; i += kBlock) {
        float c0 = lut3d[3 * i], c1 = lut3d[3 * i + 1], c2 = lut3d[3 * i + 2];
        __half2 h01 = __floats2half2_rn(c0, c1);
        __half2 h2p = __floats2half2_rn(c2, 0.0f);
        uint2 e;
        e.x = *reinterpret_cast<unsigned int*>(&h01);
        e.y = *reinterpret_cast<unsigned int*>(&h2p);
        s3[i] = e;
    }
    for (int i = threadIdx.x; i < 3 * 64; i += kBlock) {
        int c = i >> 6, j = i & 63;
        float a = lut1d[(c << 6) + j];
        float b = lut1d[(c << 6) + (j < 63 ? j + 1 : 63)];
        s1[i] = make_float2(a, b);
    }
    __syncthreads();

    const int tid = blockIdx.x * kBlock + threadIdx.x;
    const int nthreads = kGrid * kBlock;

    for (int q = tid; q < kNPair; q += nthreads) {
        const int b   = q >> 19;                       // image index
        const int rem = q & (kPairsPerImage - 1);      // pair within image
        const size_t pR = (size_t)(b * 3 + 0) * kHW + 2 * (size_t)rem;
        const size_t pG = (size_t)(b * 3 + 1) * kHW + 2 * (size_t)rem;
        const size_t pB = (size_t)(b * 3 + 2) * kHW + 2 * (size_t)rem;

        // Streaming data: non-temporal (no L2 allocate; only the LDS-resident
        // LUTs benefit from caching, x/out are touched exactly once).
        const f32x2 r2 = __builtin_nontemporal_load((const f32x2*)(x + pR));
        const f32x2 g2 = __builtin_nontemporal_load((const f32x2*)(x + pG));
        const f32x2 b2 = __builtin_nontemporal_load((const f32x2*)(x + pB));

        float ro[2], go[2], bo[2];
        const float rin[2] = {r2.x, r2.y};
        const float gin[2] = {g2.x, g2.y};
        const float bin[2] = {b2.x, b2.y};

        #pragma unroll
        for (int k = 0; k < 2; ++k) {
            float yr = apply1d(s1, 0, rin[k]);
            float yg = apply1d(s1, 1, gin[k]);
            float yb = apply1d(s1, 2, bin[k]);
            yr = fminf(fmaxf(yr, 0.0f), 1.0f);
            yg = fminf(fmaxf(yg, 0.0f), 1.0f);
            yb = fminf(fmaxf(yb, 0.0f), 1.0f);

            F3 v = tri3d(s3, yr, yg, yb);
            ro[k] = v.x; go[k] = v.y; bo[k] = v.z;
        }

        f32x2 oR; oR.x = ro[0]; oR.y = ro[1];
        f32x2 oG; oG.x = go[0]; oG.y = go[1];
        f32x2 oB; oB.x = bo[0]; oB.y = bo[1];
        __builtin_nontemporal_store(oR, (f32x2*)(out + pR));
        __builtin_nontemporal_store(oG, (f32x2*)(out + pG));
        __builtin_nontemporal_store(oB, (f32x2*)(out + pB));
    }
}

extern "C" void kernel_launch(void* const* d_in, const int* in_sizes, int n_in,
                              void* d_out, int out_size, void* d_ws, size_t ws_size,
                              hipStream_t stream) {
    const float* x     = (const float*)d_in[0];
    const float* lut1d = (const float*)d_in[1];
    const float* lut3d = (const float*)d_in[2];
    float* out = (float*)d_out;

    hipLaunchKernelGGL(lut_apply_kernel, dim3(kGrid), dim3(kBlock), 0, stream,
                       x, lut1d, lut3d, out);
}

// Round 4
// 108.578 us; speedup vs baseline: 1.0458x; 1.0242x over previous
//
#include <hip/hip_runtime.h>
#include <hip/hip_fp16.h>

// Problem constants (match reference)
constexpr int kHW = 1024 * 1024;
constexpr int kB  = 4;
constexpr int kPairsPerImage = kHW / 2;             // 524288 = 2^19
constexpr int kNPair = kB * kPairsPerImage;         // 2097152 float2-chunks
constexpr int kM  = 17;
constexpr int kM3 = kM * kM * kM;                   // 4913 cells

constexpr int kBlock = 512;
constexpr int kGrid  = 1024;                        // exactly 4 blocks/CU resident on 256 CUs

__device__ __forceinline__ float h2f_lo(unsigned int u) {
    __half2 h = *reinterpret_cast<__half2*>(&u);
    return __low2float(h);
}

// 1D LUT lerp from (base, delta) LDS table: s1[c*64+i] = (l[i], l[i+1]-l[i]).
// delta precomputed in fp32 at staging == the same fp32 subtraction the lerp
// used to do at runtime -> bit-identical results, 1 fewer VALU op per lookup.
__device__ __forceinline__ float apply1d(const float2* __restrict__ s1, int c, float v) {
    float xs = v * 63.0f;
    int i0 = (int)xs;
    i0 = min(max(i0, 0), 62);
    float f = xs - (float)i0;
    float2 p = s1[(c << 6) + i0];
    return fmaf(f, p.y, p.x);
}

struct F3 { float x, y, z; };

// Trilinear from fp16-packed LDS LUT: s3[cell] = {h(c0)|h(c1), h(c2)|0}
__device__ __forceinline__ F3 tri3d(const uint2* __restrict__ s3,
                                    float yr, float yg, float yb) {
    float xr = yr * 16.0f, xg = yg * 16.0f, xb = yb * 16.0f;
    int ir = min((int)xr, 15);
    int ig = min((int)xg, 15);
    int ib = min((int)xb, 15);
    float fr = xr - (float)ir;
    float fg = xg - (float)ig;
    float fb = xb - (float)ib;

    const int cell = (ir * 17 + ig) * 17 + ib;      // db=1, dg=17, dr=289

    // One 16B LDS read per (r,g) corner pair fetches both b corners.
    auto blerp = [&](const uint2* __restrict__ p) -> F3 {
        uint2 e0 = p[0];   // b corner
        uint2 e1 = p[1];   // b+1 corner
        float2 a01 = __half22float2(*reinterpret_cast<__half2*>(&e0.x));
        float  a2  = h2f_lo(e0.y);
        float2 b01 = __half22float2(*reinterpret_cast<__half2*>(&e1.x));
        float  b2  = h2f_lo(e1.y);
        F3 r;
        r.x = fmaf(fb, b01.x - a01.x, a01.x);
        r.y = fmaf(fb, b01.y - a01.y, a01.y);
        r.z = fmaf(fb, b2 - a2, a2);
        return r;
    };

    F3 v00 = blerp(s3 + cell);            // (r0,g0)
    F3 v01 = blerp(s3 + cell + 17);       // (r0,g1)
    F3 v10 = blerp(s3 + cell + 289);      // (r1,g0)
    F3 v11 = blerp(s3 + cell + 306);      // (r1,g1)

    F3 v0, v1, vf;
    v0.x = fmaf(fg, v01.x - v00.x, v00.x);
    v0.y = fmaf(fg, v01.y - v00.y, v00.y);
    v0.z = fmaf(fg, v01.z - v00.z, v00.z);
    v1.x = fmaf(fg, v11.x - v10.x, v10.x);
    v1.y = fmaf(fg, v11.y - v10.y, v10.y);
    v1.z = fmaf(fg, v11.z - v10.z, v10.z);
    vf.x = fmaf(fr, v1.x - v0.x, v0.x);
    vf.y = fmaf(fr, v1.y - v0.y, v0.y);
    vf.z = fmaf(fr, v1.z - v0.z, v0.z);
    return vf;
}

// __launch_bounds__(512, 8): min 8 waves/EU -> 64-VGPR cap. Essential:
// LDS is 40,840 B (rounds to 40,960 = 160KiB/4), so 4 blocks/CU fit IFF
// VGPRs <= 64. Round-1 A/B: removing this bound cost ~30% (occupancy
// 8 -> ~4 waves/SIMD; the random-LDS-gather latency stops being hidden).
// Round-3 A/B: nontemporal loads/stores cost ~5us (lost L2 write-combining)
// -- keep plain global accesses.
__global__ __launch_bounds__(kBlock, 8) void lut_apply_kernel(
    const float* __restrict__ x,
    const float* __restrict__ lut1d,   // [3][64]
    const float* __restrict__ lut3d,   // [17][17][17][3]
    float* __restrict__ out)
{
    __shared__ uint2  s3[kM3];         // 39,304 B  fp16-packed 3D LUT
    __shared__ float2 s1[3 * 64];      //  1,536 B  fp32 (base,delta) 1D LUT
                                       // total 40,840 B -> 4 blocks/CU

    for (int i = threadIdx.x; i < kM3; i += kBlock) {
        float c0 = lut3d[3 * i], c1 = lut3d[3 * i + 1], c2 = lut3d[3 * i + 2];
        __half2 h01 = __floats2half2_rn(c0, c1);
        __half2 h2p = __floats2half2_rn(c2, 0.0f);
        uint2 e;
        e.x = *reinterpret_cast<unsigned int*>(&h01);
        e.y = *reinterpret_cast<unsigned int*>(&h2p);
        s3[i] = e;
    }
    for (int i = threadIdx.x; i < 3 * 64; i += kBlock) {
        int c = i >> 6, j = i & 63;
        float a = lut1d[(c << 6) + j];
        float b = lut1d[(c << 6) + (j < 63 ? j + 1 : 63)];
        s1[i] = make_float2(a, b - a);
    }
    __syncthreads();

    const int tid = blockIdx.x * kBlock + threadIdx.x;
    const int nthreads = kGrid * kBlock;

    for (int q = tid; q < kNPair; q += nthreads) {
        const int b   = q >> 19;                       // image index
        const int rem = q & (kPairsPerImage - 1);      // pair within image
        const size_t pR = (size_t)(b * 3 + 0) * kHW + 2 * (size_t)rem;
        const size_t pG = (size_t)(b * 3 + 1) * kHW + 2 * (size_t)rem;
        const size_t pB = (size_t)(b * 3 + 2) * kHW + 2 * (size_t)rem;

        const float2 r2 = *(const float2*)(x + pR);
        const float2 g2 = *(const float2*)(x + pG);
        const float2 b2 = *(const float2*)(x + pB);

        float ro[2], go[2], bo[2];
        const float rin[2] = {r2.x, r2.y};
        const float gin[2] = {g2.x, g2.y};
        const float bin[2] = {b2.x, b2.y};

        #pragma unroll
        for (int k = 0; k < 2; ++k) {
            float yr = apply1d(s1, 0, rin[k]);
            float yg = apply1d(s1, 1, gin[k]);
            float yb = apply1d(s1, 2, bin[k]);
            yr = fminf(fmaxf(yr, 0.0f), 1.0f);
            yg = fminf(fmaxf(yg, 0.0f), 1.0f);
            yb = fminf(fmaxf(yb, 0.0f), 1.0f);

            F3 v = tri3d(s3, yr, yg, yb);
            ro[k] = v.x; go[k] = v.y; bo[k] = v.z;
        }

        *(float2*)(out + pR) = make_float2(ro[0], ro[1]);
        *(float2*)(out + pG) = make_float2(go[0], go[1]);
        *(float2*)(out + pB) = make_float2(bo[0], bo[1]);
    }
}

extern "C" void kernel_launch(void* const* d_in, const int* in_sizes, int n_in,
                              void* d_out, int out_size, void* d_ws, size_t ws_size,
                              hipStream_t stream) {
    const float* x     = (const float*)d_in[0];
    const float* lut1d = (const float*)d_in[1];
    const float* lut3d = (const float*)d_in[2];
    float* out = (float*)d_out;

    hipLaunchKernelGGL(lut_apply_kernel, dim3(kGrid), dim3(kBlock), 0, stream,
                       x, lut1d, lut3d, out);
}